// Round 7
// baseline (34.181 us; speedup 1.0000x reference)
//
#include <hip/hip_runtime.h>
#include <math.h>

#define SEQ 8192
#define HID 2048
#define NC4 (HID / 4)   // 512 float4 per row

// Workspace (floats):
//   m     [0,    2048)
//   v     [2048, 4096)
//   energ [4096, 12288)

// ---------------------------------------------------------------------------
// K1: blocks 0..255   -> m[row] = W_pq[row,:].pool + b_pq[row] (8 rows/block)
//     blocks 256..511 -> v[8 cols]: stream all 2048 rows of an 8-col slab,
//                        LDS tree-reduce over 128 row-phases. No vpart.
// ---------------------------------------------------------------------------
__global__ __launch_bounds__(256) void k1(const float* __restrict__ pool,
                                          const float* __restrict__ W_pq,
                                          const float* __restrict__ b_pq,
                                          const float* __restrict__ hidden,
                                          const float* __restrict__ W_qh,
                                          float* __restrict__ m,
                                          float* __restrict__ v) {
  const int tid  = threadIdx.x;
  const int wave = tid >> 6;
  const int lane = tid & 63;
  const int bid  = blockIdx.x;

  if (bid < 256) {
    const float4* p4 = reinterpret_cast<const float4*>(pool);
    const int row0 = bid * 8 + wave * 2;
    const float4* W0 = reinterpret_cast<const float4*>(W_pq + (size_t)row0 * HID);
    const float4* W1 = reinterpret_cast<const float4*>(W_pq + (size_t)(row0 + 1) * HID);
    float acc0 = 0.f, acc1 = 0.f;
    #pragma unroll
    for (int j = 0; j < 8; ++j) {
      const int i = lane + j * 64;
      float4 p = p4[i];
      float4 w0 = W0[i], w1 = W1[i];
      acc0 += w0.x * p.x + w0.y * p.y + w0.z * p.z + w0.w * p.w;
      acc1 += w1.x * p.x + w1.y * p.y + w1.z * p.z + w1.w * p.w;
    }
    #pragma unroll
    for (int off = 32; off; off >>= 1) {
      acc0 += __shfl_down(acc0, off, 64);
      acc1 += __shfl_down(acc1, off, 64);
    }
    if (lane == 0) {
      m[row0]     = acc0 + b_pq[row0];
      m[row0 + 1] = acc1 + b_pq[row0 + 1];
    }
  } else {
    // v: block owns float4 columns {c8*2, c8*2+1}; thread (rph, fq) streams
    // rows rph+128*i. Thread-pairs read contiguous 32 B; granule-aligned.
    __shared__ float4 arr[256];
    const int c8  = bid - 256;        // 0..255
    const int fq  = tid & 1;
    const int rph = tid >> 1;         // 0..127
    const int c4  = c8 * 2 + fq;
    float4 acc = {0.f, 0.f, 0.f, 0.f};
    #pragma unroll
    for (int i = 0; i < 16; ++i) {
      const int r = rph + i * 128;
      const float  h = hidden[r];
      const float4 w = reinterpret_cast<const float4*>(W_qh + (size_t)r * HID)[c4];
      acc.x += h * w.x; acc.y += h * w.y; acc.z += h * w.z; acc.w += h * w.w;
    }
    arr[tid] = acc;
    __syncthreads();
    #pragma unroll
    for (int s = 64; s >= 1; s >>= 1) {
      if (rph < s) {
        const float4 o = arr[(rph + s) * 2 + fq];
        acc.x += o.x; acc.y += o.y; acc.z += o.z; acc.w += o.w;
        arr[tid] = acc;
      }
      __syncthreads();
    }
    if (rph == 0) reinterpret_cast<float4*>(v)[c4] = acc;
  }
}

// ---------------------------------------------------------------------------
// K2: 1024 blocks x 8 rows. Prologue: g = m*v (2 loads/thread) -> LDS -> regs.
// Main: each wave does 2 rows with ALL 16 float4 loads issued before FMAs.
// ---------------------------------------------------------------------------
__global__ __launch_bounds__(256, 4) void k2(const float* __restrict__ enc,
                                             const float* __restrict__ m,
                                             const float* __restrict__ v,
                                             float* __restrict__ energ) {
  __shared__ float4 gl[NC4];    // 8 KB
  const int tid  = threadIdx.x;
  const int wave = tid >> 6;
  const int lane = tid & 63;
  const int bid  = blockIdx.x;

  const float4* m4 = reinterpret_cast<const float4*>(m);
  const float4* v4 = reinterpret_cast<const float4*>(v);
  #pragma unroll
  for (int j = 0; j < 2; ++j) {
    const int c = tid + j * 256;
    const float4 mm = m4[c], vv = v4[c];
    float4 g = {mm.x * vv.x, mm.y * vv.y, mm.z * vv.z, mm.w * vv.w};
    gl[c] = g;
  }
  __syncthreads();

  float4 greg[8];
  #pragma unroll
  for (int j = 0; j < 8; ++j) greg[j] = gl[lane + j * 64];

  const int row0 = bid * 8 + wave * 2;
  const float4* E0 = reinterpret_cast<const float4*>(enc + (size_t)row0 * HID);
  const float4* E1 = reinterpret_cast<const float4*>(enc + (size_t)(row0 + 1) * HID);

  // issue all 16 loads, then FMA
  float4 e0[8], e1[8];
  #pragma unroll
  for (int j = 0; j < 8; ++j) e0[j] = E0[lane + j * 64];
  #pragma unroll
  for (int j = 0; j < 8; ++j) e1[j] = E1[lane + j * 64];

  float acc0 = 0.f, acc1 = 0.f;
  #pragma unroll
  for (int j = 0; j < 8; ++j) {
    const float4 g = greg[j];
    acc0 += e0[j].x * g.x + e0[j].y * g.y + e0[j].z * g.z + e0[j].w * g.w;
    acc1 += e1[j].x * g.x + e1[j].y * g.y + e1[j].z * g.z + e1[j].w * g.w;
  }
  #pragma unroll
  for (int off = 32; off; off >>= 1) {
    acc0 += __shfl_down(acc0, off, 64);
    acc1 += __shfl_down(acc1, off, 64);
  }
  if (lane == 0) {
    energ[row0]     = acc0;
    energ[row0 + 1] = acc1;
  }
}

// ---------------------------------------------------------------------------
// K3: softmax — 32 blocks, each redundantly computes the identical global
// max/sum (float4 loads), writes its own 256 outputs. No 1-CU tail.
// ---------------------------------------------------------------------------
__global__ __launch_bounds__(256) void k3(const float* __restrict__ e,
                                          float* __restrict__ out) {
  __shared__ float red[8];
  const int tid  = threadIdx.x;
  const int wave = tid >> 6;
  const int lane = tid & 63;
  const int bid  = blockIdx.x;

  const float4* e4 = reinterpret_cast<const float4*>(e);
  float4 vals[8];
  float mx = -INFINITY;
  #pragma unroll
  for (int i = 0; i < 8; ++i) {
    vals[i] = e4[tid + i * 256];
    mx = fmaxf(mx, fmaxf(fmaxf(vals[i].x, vals[i].y), fmaxf(vals[i].z, vals[i].w)));
  }
  #pragma unroll
  for (int off = 32; off; off >>= 1) mx = fmaxf(mx, __shfl_down(mx, off, 64));
  if (lane == 0) red[wave] = mx;
  __syncthreads();
  const float bm = fmaxf(fmaxf(red[0], red[1]), fmaxf(red[2], red[3]));

  float s = 0.f;
  #pragma unroll
  for (int i = 0; i < 8; ++i) {
    s += expf(vals[i].x - bm) + expf(vals[i].y - bm) +
         expf(vals[i].z - bm) + expf(vals[i].w - bm);
  }
  #pragma unroll
  for (int off = 32; off; off >>= 1) s += __shfl_down(s, off, 64);
  if (lane == 0) red[4 + wave] = s;
  __syncthreads();
  const float inv = 1.f / (red[4] + red[5] + red[6] + red[7]);

  const int row = bid * 256 + tid;
  out[row] = expf(e[row] - bm) * inv;
}

// ---------------------------------------------------------------------------
extern "C" void kernel_launch(void* const* d_in, const int* in_sizes, int n_in,
                              void* d_out, int out_size, void* d_ws, size_t ws_size,
                              hipStream_t stream) {
  const float* hidden = (const float*)d_in[0];  // (1, 2048)
  const float* enc    = (const float*)d_in[1];  // (8192, 2048)
  const float* pool   = (const float*)d_in[2];  // (1, 2048)
  const float* W_pq   = (const float*)d_in[3];  // (2048, 2048)
  const float* b_pq   = (const float*)d_in[4];  // (2048,)
  const float* W_qh   = (const float*)d_in[5];  // (2048, 2048)
  // d_in[6] = b_qh — uniform shift over seq, cancels in softmax.

  float* out   = (float*)d_out;
  float* ws    = (float*)d_ws;
  float* m     = ws;             // 2048
  float* v     = ws + HID;       // 2048
  float* energ = ws + 2 * HID;   // 8192

  k1<<<dim3(512), dim3(256), 0, stream>>>(pool, W_pq, b_pq, hidden, W_qh, m, v);
  k2<<<dim3(1024), dim3(256), 0, stream>>>(enc, m, v, energ);
  k3<<<dim3(32), dim3(256), 0, stream>>>(energ, out);
}